// Round 14
// baseline (191.059 us; speedup 1.0000x reference)
//
#include <hip/hip_runtime.h>
#include <hip/hip_fp16.h>

#define N_NODES 50000
#define N_EDGES 800000
#define NBKT 196            // ceil(50000 / 256) coarse buckets (dst >> 8)
#define BCAP 4480           // fixed bucket capacity: mean 4083, sd 64 -> +6 sigma
#define EPB_BIN 4096        // edges per staging block
#define NB_BIN ((N_EDGES + EPB_BIN - 1) / EPB_BIN)   // 196
#define NB_EL 196           // ceil(50000/256) blocks for el9p role
#define NB_PW 48            // 64*192/256 blocks for prepW role

typedef _Float16 half8 __attribute__((ext_vector_type(8)));
typedef float f32x4 __attribute__((ext_vector_type(4)));

static __device__ __forceinline__ float lrelu(float x) { return fmaxf(x, 0.2f * x); }

static __device__ __forceinline__ float2 h2f(float bits) {
    union { float f; __half2 h; } u;
    u.f = bits;
    return __half22float2(u.h);
}
static __device__ __forceinline__ float f2h2(float a, float b) {
    union { float f; __half2 h; } u;
    u.h = __floats2half2_rn(a, b);
    return u.f;
}

// ---------------- fused front kernel: stage | el9p | prepW | prepA ----------
__global__ void __launch_bounds__(256) k_front(const int* __restrict__ src,
                                               const int* __restrict__ dst,
                                               int* __restrict__ bfill,
                                               unsigned int* __restrict__ stage,
                                               const float* __restrict__ x,
                                               const float* __restrict__ W1,
                                               const float* __restrict__ al1,
                                               const float* __restrict__ ar1,
                                               float* __restrict__ xph,
                                               float* __restrict__ er,
                                               const float* __restrict__ W2,
                                               __half* __restrict__ Wt16,
                                               const float* __restrict__ al2,
                                               const float* __restrict__ ar2,
                                               float* __restrict__ Wa2,
                                               float* __restrict__ Wr2) {
    __shared__ int lcnt[NBKT];
    __shared__ int gb[NBKT];
    __shared__ int lf[NBKT];
    __shared__ float sWa[9 * 3];
    __shared__ float sWr[9 * 3];
    const int t = threadIdx.x;
    const int b = blockIdx.x;

    if (b < NB_BIN) {
        // ---- role: stage edges into fixed-capacity buckets ----
        const int e0 = b * EPB_BIN;
        for (int i = t; i < NBKT; i += 256) lcnt[i] = 0;
        __syncthreads();
        int dcache[16];
#pragma unroll
        for (int i = 0; i < 16; ++i) {
            const int e = e0 + i * 256 + t;
            if (e < N_EDGES) {
                const int d = dst[e];
                dcache[i] = d;
                atomicAdd(&lcnt[d >> 8], 1);
            } else dcache[i] = -1;
        }
        __syncthreads();
        for (int i = t; i < NBKT; i += 256) {
            gb[i] = i * BCAP + atomicAdd(&bfill[i], lcnt[i]);
            lf[i] = 0;
        }
        __syncthreads();
#pragma unroll
        for (int i = 0; i < 16; ++i) {
            const int e = e0 + i * 256 + t;
            if (e < N_EDGES) {
                const int d = dcache[i];
                const int bk = d >> 8;
                const int r = atomicAdd(&lf[bk], 1);
                stage[gb[bk] + r] = (unsigned int)src[e] | ((unsigned int)(d & 255) << 16);
            }
        }
        return;
    }
    if (b < NB_BIN + NB_EL) {
        // ---- role: layer-1 packed features + er ----
        if (t < 27) {
            const int h = t / 9, k = t % 9;
            float sa = 0.f, sr = 0.f;
            for (int f = 0; f < 64; ++f) {
                const float w = W1[k * 192 + h * 64 + f];
                sa += w * al1[h * 64 + f];
                sr += w * ar1[h * 64 + f];
            }
            sWa[k * 3 + h] = sa;
            sWr[k * 3 + h] = sr;
        }
        __syncthreads();
        const int n = (b - NB_BIN) * 256 + t;
        if (n >= N_NODES) return;
        const float* __restrict__ xr = x + (size_t)n * 9;
        float xv[9];
        float a0 = 0.f, a1 = 0.f, a2 = 0.f, r0 = 0.f, r1 = 0.f, r2 = 0.f;
#pragma unroll
        for (int k = 0; k < 9; ++k) {
            xv[k] = xr[k];
            a0 += xv[k] * sWa[k * 3 + 0];
            a1 += xv[k] * sWa[k * 3 + 1];
            a2 += xv[k] * sWa[k * 3 + 2];
            r0 += xv[k] * sWr[k * 3 + 0];
            r1 += xv[k] * sWr[k * 3 + 1];
            r2 += xv[k] * sWr[k * 3 + 2];
        }
        float* __restrict__ xo = xph + (size_t)n * 8;
        *reinterpret_cast<float4*>(xo) = make_float4(a0, a1, a2, f2h2(xv[0], xv[1]));
        *reinterpret_cast<float4*>(xo + 4) =
            make_float4(f2h2(xv[2], xv[3]), f2h2(xv[4], xv[5]),
                        f2h2(xv[6], xv[7]), f2h2(xv[8], 0.f));
        *reinterpret_cast<float4*>(er + (size_t)n * 4) = make_float4(r0, r1, r2, 0.f);
        return;
    }
    if (b < NB_BIN + NB_EL + NB_PW) {
        // ---- role: W2 -> fp16 effective-transpose table ----
        const int idx = (b - (NB_BIN + NB_EL)) * 256 + t;
        if (idx < 64 * 192) {
            const int n = idx / 192, ke = idx % 192;
            Wt16[idx] = __float2half(W2[(ke & 63) * 192 + (ke >> 6) * 64 + n]);
        }
        return;
    }
    // ---- role: Wa2/Wr2 precompute ----
    if (t < 192) {
        const int h = t >> 6, k = t & 63;
        float sa = 0.f, sr = 0.f;
        for (int f = 0; f < 64; ++f) {
            const float w = W2[k * 192 + h * 64 + f];
            sa += w * al2[h * 64 + f];
            sr += w * ar2[h * 64 + f];
        }
        Wa2[k * 4 + h] = sa;
        Wr2[k * 4 + h] = sr;
        if (h == 0) { Wa2[k * 4 + 3] = 0.f; Wr2[k * 4 + 3] = 0.f; }
    }
}

// ---------------- per bucket scatter v2: shfl scans --------------------------
__global__ void __launch_bounds__(512) k_bscatter2(const unsigned int* __restrict__ stage,
                                                   const int* __restrict__ bfill,
                                                   int* __restrict__ rowp,
                                                   int* __restrict__ col) {
    __shared__ int lcnt[256];
    __shared__ int sexc[256];
    __shared__ int wsum[8];
    __shared__ int sbase;
    const int t = threadIdx.x;
    const int lane = t & 63;
    const int w = t >> 6;
    const int b = blockIdx.x;
    const int n0 = b << 8;

    int p = (t < b) ? bfill[t] : 0;
#pragma unroll
    for (int off = 32; off > 0; off >>= 1) p += __shfl_xor(p, off);
    if (lane == 0) wsum[w] = p;
    if (t < 256) lcnt[t] = 0;
    __syncthreads();
    if (t == 0) {
        int s = 0;
#pragma unroll
        for (int i = 0; i < 8; ++i) s += wsum[i];
        sbase = s;
    }
    const int cnt = bfill[b];
    const unsigned int* __restrict__ st = stage + (size_t)b * BCAP;
    for (int j = t; j < cnt; j += 512)
        atomicAdd(&lcnt[(st[j] >> 16) & 255], 1);
    __syncthreads();
    int v = 0, s = 0;
    if (t < 256) {
        v = lcnt[t];
        s = v;
#pragma unroll
        for (int off = 1; off < 64; off <<= 1) {
            const int u = __shfl_up(s, off);
            if (lane >= off) s += u;
        }
        if (lane == 63) wsum[w] = s;
    }
    __syncthreads();
    const int base = sbase;
    if (t < 256) {
        int add = 0;
        for (int i = 0; i < w; ++i) add += wsum[i];
        const int exc = s + add - v;
        sexc[t] = exc;
        if (n0 + t < N_NODES) rowp[n0 + t] = base + exc;
        lcnt[t] = 0;   // reuse as fill counters
    }
    if (b == NBKT - 1 && t == 0) rowp[N_NODES] = N_EDGES;
    __syncthreads();
    for (int j = t; j < cnt; j += 512) {
        const unsigned int e = st[j];
        const int local = (int)(e >> 16) & 255;
        const int r = atomicAdd(&lcnt[local], 1);
        col[base + sexc[local] + r] = (int)(e & 0xFFFFu);
    }
}

// ---------------- fused L1 v6: 2x5-lane split x-phase, padded wbuf ----------
// (a) wbuf padded [4][4][17]: quarters' rows were 256B apart -> same bank,
//     4-way conflict on every read (1.4M conflict cycles measured r13).
// (b) x-phase edges split across two 5-lane groups (lanes 0-4: edges 0-7,
//     lanes 8-12: edges 8-15) -> halves the serial load+FMA chain; one
//     6-value shfl_xor(8) combine after the loop. Latency-targeted (the
//     addr-count and byte-count theories were falsified r12/r13).
__global__ void __launch_bounds__(256, 6) k_l1(const float* __restrict__ xph,
                                               const float* __restrict__ er_in,
                                               const int* __restrict__ rowp,
                                               const int* __restrict__ col,
                                               const float* __restrict__ W1,
                                               const float* __restrict__ b1,
                                               const float* __restrict__ Wa2,
                                               const float* __restrict__ Wr2,
                                               signed char* __restrict__ hout8,
                                               float* __restrict__ el,
                                               float* __restrict__ er_out) {
    __shared__ float4 wbuf[4][4][17];   // padded: kills 4-way bank conflict
    __shared__ union {
        float At[16 * 28];          // agg -> gemm handoff (dead after part compute)
        float vbuf[16][72];         // gemm epilogue staging (aliases At; sync between)
    } u;
    __shared__ float part[3][16][64];
    __shared__ float sscale[16];
    const int t = threadIdx.x;
    const int wv = t >> 6;
    const int lane = t & 63;
    const int q = lane >> 4;            // node slot within wave
    const int ql = lane & 15;           // lane within quarter
    const int li = wv * 4 + q;          // local node 0..15
    const int nbase = blockIdx.x * 16;  // 3125 * 16 = 50000 exact
    const int n = nbase + li;
    const char* __restrict__ xb = (const char*)xph;

    // ---- aggregation: el-phase lane/edge, x-phase 2x5-lane groups ----
    {
        const int jb = rowp[n], je = rowp[n + 1];
        const float4 er4 = *reinterpret_cast<const float4*>(er_in + (size_t)n * 4);
        const int fl = (ql < 8) ? ql : ql - 8;       // feature-pair index in group
        const bool active = (fl < 5);
        const int fo = 12 + 4 * fl;                  // lane's half2 byte offset
        const bool hiGroup = (ql >= 8);
        float a00 = 0.f, a01 = 0.f, a10 = 0.f, a11 = 0.f, a20 = 0.f, a21 = 0.f;
        float sw0 = 0.f, sw1 = 0.f, sw2 = 0.f;

        for (int c0 = jb; c0 < je; c0 += 16) {
            const int cnt = min(16, je - c0);
            if (ql < cnt) {
                const int s = col[c0 + ql];
                const float4 e4 = *reinterpret_cast<const float4*>(xb + (s << 5));
                const float w0 = __expf(lrelu(e4.x + er4.x));
                const float w1 = __expf(lrelu(e4.y + er4.y));
                const float w2 = __expf(lrelu(e4.z + er4.z));
                wbuf[wv][q][ql] = make_float4(w0, w1, w2, __int_as_float(s << 5));
                sw0 += w0; sw1 += w1; sw2 += w2;
            }
            __builtin_amdgcn_wave_barrier();
            if (active) {
                int k = hiGroup ? 8 : 0;
                const int ke = hiGroup ? cnt : min(cnt, 8);
                for (; k + 2 <= ke; k += 2) {
                    const float4 q0 = wbuf[wv][q][k];
                    const float4 q1 = wbuf[wv][q][k + 1];
                    const float2 f0 = h2f(*reinterpret_cast<const float*>(
                        xb + (__float_as_int(q0.w) + fo)));
                    const float2 f1 = h2f(*reinterpret_cast<const float*>(
                        xb + (__float_as_int(q1.w) + fo)));
                    a00 += q0.x * f0.x + q1.x * f1.x;
                    a01 += q0.x * f0.y + q1.x * f1.y;
                    a10 += q0.y * f0.x + q1.y * f1.x;
                    a11 += q0.y * f0.y + q1.y * f1.y;
                    a20 += q0.z * f0.x + q1.z * f1.x;
                    a21 += q0.z * f0.y + q1.z * f1.y;
                }
                if (k < ke) {
                    const float4 q0 = wbuf[wv][q][k];
                    const float2 f0 = h2f(*reinterpret_cast<const float*>(
                        xb + (__float_as_int(q0.w) + fo)));
                    a00 += q0.x * f0.x; a01 += q0.x * f0.y;
                    a10 += q0.y * f0.x; a11 += q0.y * f0.y;
                    a20 += q0.z * f0.x; a21 += q0.z * f0.y;
                }
            }
        }
        // combine the two 5-lane groups (lane ql gets ql^8's partials)
        a00 += __shfl_xor(a00, 8); a01 += __shfl_xor(a01, 8);
        a10 += __shfl_xor(a10, 8); a11 += __shfl_xor(a11, 8);
        a20 += __shfl_xor(a20, 8); a21 += __shfl_xor(a21, 8);
        // sw reduce within the 16-lane quarter
#pragma unroll
        for (int off = 1; off < 16; off <<= 1) {
            sw0 += __shfl_xor(sw0, off);
            sw1 += __shfl_xor(sw1, off);
            sw2 += __shfl_xor(sw2, off);
        }
        if (ql < 5) {
            const bool has = (je > jb);
            const float i0 = has ? 1.f / sw0 : 0.f;
            const float i1 = has ? 1.f / sw1 : 0.f;
            const float i2 = has ? 1.f / sw2 : 0.f;
            float* __restrict__ ao = u.At + li * 28;
            const int f = 2 * ql;
            ao[f] = a00 * i0;
            ao[9 + f] = a10 * i1;
            ao[18 + f] = a20 * i2;
            if (ql < 4) {                // f8's pair slot is head-1's slot 9 — guard
                ao[f + 1] = a01 * i0;
                ao[9 + f + 1] = a11 * i1;
                ao[18 + f + 1] = a21 * i2;
            }
        }
    }
    __syncthreads();

    // ---- GEMM (h = wave id, c = lane) + int8 quantized store ----
    {
        const int h = wv;               // 0..3; h==3 idle for partials
        const int c = lane;
        if (h < 3) {
            float wreg[9];
#pragma unroll
            for (int k = 0; k < 9; ++k) wreg[k] = W1[k * 192 + h * 64 + c];
#pragma unroll
            for (int i = 0; i < 16; ++i) {
                const float* __restrict__ arp = u.At + i * 28 + h * 9;
                float acc = 0.f;
#pragma unroll
                for (int k = 0; k < 9; ++k) acc += arp[k] * wreg[k];
                part[h][i][c] = acc;
            }
        }
        __syncthreads();
        const float bsum = b1[c] + b1[64 + c] + b1[128 + c];
        for (int idx = t; idx < 1024; idx += 256) {
            const int i = idx >> 6, cc = idx & 63;  // cc == lane; wave owns node i
            const float v = part[0][i][cc] + part[1][i][cc] + part[2][i][cc] + bsum;
            u.vbuf[i][cc] = v;           // aliases At — legal: At dead, sync above
            float av = fabsf(v);
#pragma unroll
            for (int off = 32; off > 0; off >>= 1) av = fmaxf(av, __shfl_xor(av, off));
            const float inv = (av > 0.f) ? 127.f / av : 0.f;
            hout8[(size_t)(nbase + i) * 64 + cc] = (signed char)__float2int_rn(v * inv);
            if (cc == 0) sscale[i] = av * (1.f / 127.f);
        }
        __syncthreads();
        if (t < 96) {
            const int i = t / 6, r = t % 6;
            const int h3 = (r < 3) ? r : r - 3;
            const float* __restrict__ tab = (r < 3) ? Wa2 : Wr2;
            float s = 0.f;
#pragma unroll 8
            for (int c2 = 0; c2 < 64; ++c2) s += u.vbuf[i][c2] * tab[c2 * 4 + h3];
            if (r < 3) el[(size_t)(nbase + i) * 4 + h3] = s;
            else       er_out[(size_t)(nbase + i) * 4 + h3] = s;
        } else if (t < 112) {
            const int i = t - 96;        // scale rides in el.w (was unused pad)
            el[(size_t)(nbase + i) * 4 + 3] = sscale[i];
        }
    }
}

// ---------------- fused L2: int8-gather agg + MFMA GEMM + L3 features --------
__global__ void __launch_bounds__(256, 6) k_l2(const signed char* __restrict__ x8,
                                               const float* __restrict__ el,
                                               const float* __restrict__ er,
                                               const int* __restrict__ rowp,
                                               const int* __restrict__ col,
                                               const __half* __restrict__ Wt,
                                               const float* __restrict__ b2,
                                               const float* __restrict__ W3,
                                               const float* __restrict__ al3,
                                               const float* __restrict__ ar3,
                                               float* __restrict__ feat3p,
                                               float* __restrict__ er3) {
    __shared__ float4 wbuf[4][4][17];     // padded: kills 4-way bank conflict
    __shared__ __half aggL[16][200];      // 6.25 KB (pad 192->200)
    __shared__ float xl[16 * 68];         // 4.25 KB
    __shared__ float Wl[384];
    __shared__ float Wal[192];
    __shared__ float Wrl[192];
    const int t = threadIdx.x;
    const int wv = t >> 6;
    const int lane = t & 63;
    const int q = lane >> 4;              // node slot within wave
    const int ql = lane & 15;             // lane within quarter
    const int li = wv * 4 + q;            // local node 0..15
    const int nbase = blockIdx.x * 16;    // 3125 * 16 = 50000 exact
    const int n = nbase + li;

    // ---- Phase A: aggregation (int8 gather, 4B/lane) ----
    {
        const int jb = rowp[n], je = rowp[n + 1];
        const float4 er4 = *reinterpret_cast<const float4*>(er + (size_t)n * 4);
        const char* __restrict__ xbase = (const char*)x8;
        const char* __restrict__ elbase = (const char*)el;
        const int foff = ql * 4;          // 4 int8 feats per lane

        float acc[12];
#pragma unroll
        for (int j = 0; j < 12; ++j) acc[j] = 0.f;
        float sw0 = 0.f, sw1 = 0.f, sw2 = 0.f;

        for (int c0 = jb; c0 < je; c0 += 16) {
            const int cnt = min(16, je - c0);
            if (ql < cnt) {
                const int s = col[c0 + ql];
                const float4 e4 = *reinterpret_cast<const float4*>(elbase + (s << 4));
                const float w0 = __expf(lrelu(e4.x + er4.x));
                const float w1 = __expf(lrelu(e4.y + er4.y));
                const float w2 = __expf(lrelu(e4.z + er4.z));
                sw0 += w0; sw1 += w1; sw2 += w2;
                // fold dequant scale (el.w) into the weights; sw stays unscaled
                wbuf[wv][q][ql] = make_float4(w0 * e4.w, w1 * e4.w, w2 * e4.w,
                                              __int_as_float(s << 6));
            }
            __builtin_amdgcn_wave_barrier();
            int k = 0;
            for (; k + 4 <= cnt; k += 4) {
                const float4 q0 = wbuf[wv][q][k];
                const float4 q1 = wbuf[wv][q][k + 1];
                const float4 q2 = wbuf[wv][q][k + 2];
                const float4 q3 = wbuf[wv][q][k + 3];
                const int d0 = *reinterpret_cast<const int*>(xbase + (__float_as_int(q0.w) + foff));
                const int d1 = *reinterpret_cast<const int*>(xbase + (__float_as_int(q1.w) + foff));
                const int d2 = *reinterpret_cast<const int*>(xbase + (__float_as_int(q2.w) + foff));
                const int d3 = *reinterpret_cast<const int*>(xbase + (__float_as_int(q3.w) + foff));
                const float a0 = (float)(signed char)d0, a1 = (float)(signed char)(d0 >> 8),
                            a2 = (float)(signed char)(d0 >> 16), a3 = (float)(d0 >> 24);
                const float b0 = (float)(signed char)d1, b1v = (float)(signed char)(d1 >> 8),
                            b2v = (float)(signed char)(d1 >> 16), b3v = (float)(d1 >> 24);
                const float c0v = (float)(signed char)d2, c1 = (float)(signed char)(d2 >> 8),
                            c2 = (float)(signed char)(d2 >> 16), c3 = (float)(d2 >> 24);
                const float e0 = (float)(signed char)d3, e1 = (float)(signed char)(d3 >> 8),
                            e2 = (float)(signed char)(d3 >> 16), e3 = (float)(d3 >> 24);
                acc[0] += q0.x * a0 + q1.x * b0 + q2.x * c0v + q3.x * e0;
                acc[1] += q0.x * a1 + q1.x * b1v + q2.x * c1 + q3.x * e1;
                acc[2] += q0.x * a2 + q1.x * b2v + q2.x * c2 + q3.x * e2;
                acc[3] += q0.x * a3 + q1.x * b3v + q2.x * c3 + q3.x * e3;
                acc[4] += q0.y * a0 + q1.y * b0 + q2.y * c0v + q3.y * e0;
                acc[5] += q0.y * a1 + q1.y * b1v + q2.y * c1 + q3.y * e1;
                acc[6] += q0.y * a2 + q1.y * b2v + q2.y * c2 + q3.y * e2;
                acc[7] += q0.y * a3 + q1.y * b3v + q2.y * c3 + q3.y * e3;
                acc[8]  += q0.z * a0 + q1.z * b0 + q2.z * c0v + q3.z * e0;
                acc[9]  += q0.z * a1 + q1.z * b1v + q2.z * c1 + q3.z * e1;
                acc[10] += q0.z * a2 + q1.z * b2v + q2.z * c2 + q3.z * e2;
                acc[11] += q0.z * a3 + q1.z * b3v + q2.z * c3 + q3.z * e3;
            }
            for (; k < cnt; ++k) {
                const float4 q0 = wbuf[wv][q][k];
                const int d0 = *reinterpret_cast<const int*>(xbase + (__float_as_int(q0.w) + foff));
                const float a0 = (float)(signed char)d0, a1 = (float)(signed char)(d0 >> 8),
                            a2 = (float)(signed char)(d0 >> 16), a3 = (float)(d0 >> 24);
                acc[0] += q0.x * a0; acc[1] += q0.x * a1;
                acc[2] += q0.x * a2; acc[3] += q0.x * a3;
                acc[4] += q0.y * a0; acc[5] += q0.y * a1;
                acc[6] += q0.y * a2; acc[7] += q0.y * a3;
                acc[8]  += q0.z * a0; acc[9]  += q0.z * a1;
                acc[10] += q0.z * a2; acc[11] += q0.z * a3;
            }
        }
#pragma unroll
        for (int off = 1; off < 16; off <<= 1) {
            sw0 += __shfl_xor(sw0, off);
            sw1 += __shfl_xor(sw1, off);
            sw2 += __shfl_xor(sw2, off);
        }
        __half* __restrict__ ao = &aggL[li][ql * 4];
        if (je > jb) {
            const float i0 = 1.f / sw0, i1 = 1.f / sw1, i2 = 1.f / sw2;
            *reinterpret_cast<float2*>(ao) =
                make_float2(f2h2(acc[0] * i0, acc[1] * i0), f2h2(acc[2] * i0, acc[3] * i0));
            *reinterpret_cast<float2*>(ao + 64) =
                make_float2(f2h2(acc[4] * i1, acc[5] * i1), f2h2(acc[6] * i1, acc[7] * i1));
            *reinterpret_cast<float2*>(ao + 128) =
                make_float2(f2h2(acc[8] * i2, acc[9] * i2), f2h2(acc[10] * i2, acc[11] * i2));
        } else {
            const float2 z = make_float2(f2h2(0.f, 0.f), f2h2(0.f, 0.f));
            *reinterpret_cast<float2*>(ao) = z;
            *reinterpret_cast<float2*>(ao + 64) = z;
            *reinterpret_cast<float2*>(ao + 128) = z;
        }
    }
    // weight prep for phase C (disjoint LDS; before the sync)
    for (int idx = t; idx < 384; idx += 256) Wl[idx] = W3[idx];
    if (t < 192) {
        const int k = t & 63, h = t >> 6;
        Wal[k * 3 + h] = W3[k * 6 + h * 2] * al3[h * 2] + W3[k * 6 + h * 2 + 1] * al3[h * 2 + 1];
        Wrl[k * 3 + h] = W3[k * 6 + h * 2] * ar3[h * 2] + W3[k * 6 + h * 2 + 1] * ar3[h * 2 + 1];
    }
    __syncthreads();

    // ---- Phase B: MFMA hidden = aggL @ W2^T + b2sum -> xl (LDS) ----
    {
        const int quad = lane >> 4;
        const int t16 = lane & 15;
        half8 a[6];
#pragma unroll
        for (int kb = 0; kb < 6; ++kb)
            a[kb] = *reinterpret_cast<const half8*>(&aggL[t16][kb * 32 + quad * 8]);
        const int c = wv * 16 + t16;          // nt = wv
        const float bs = b2[c] + b2[64 + c] + b2[128 + c];
        const __half* __restrict__ bt = Wt + (size_t)c * 192 + quad * 8;
        f32x4 acc = {0.f, 0.f, 0.f, 0.f};
#pragma unroll
        for (int kb = 0; kb < 6; ++kb) {
            const half8 bfr = *reinterpret_cast<const half8*>(bt + kb * 32);
            acc = __builtin_amdgcn_mfma_f32_16x16x32_f16(a[kb], bfr, acc, 0, 0, 0);
        }
#pragma unroll
        for (int r = 0; r < 4; ++r)
            xl[(quad * 4 + r) * 68 + c] = acc[r] + bs;
    }
    __syncthreads();

    // ---- Phase C: layer-3 packed features for the block's 16 nodes ----
    if (t < 128) {
        const int i = t >> 3;
        const int slot = t & 7;
        if (slot < 6) {
            float acc = 0.f;
#pragma unroll
            for (int k4 = 0; k4 < 16; ++k4) {
                const float4 xv = *reinterpret_cast<const float4*>(&xl[i * 68 + 4 * k4]);
                acc += Wl[(4 * k4 + 0) * 6 + slot] * xv.x;
                acc += Wl[(4 * k4 + 1) * 6 + slot] * xv.y;
                acc += Wl[(4 * k4 + 2) * 6 + slot] * xv.z;
                acc += Wl[(4 * k4 + 3) * 6 + slot] * xv.w;
            }
            reinterpret_cast<__half*>(feat3p + (size_t)(nbase + i) * 8)[6 + slot] = __float2half(acc);
        }
    } else if (t < 224) {
        const int tt = t - 128;
        const int ii = tt / 6, ss = tt % 6;
        const int hh = (ss < 3) ? ss : ss - 3;
        const float* __restrict__ wt = (ss < 3) ? Wal : Wrl;
        float acc = 0.f;
#pragma unroll 4
        for (int k = 0; k < 64; ++k) acc += xl[ii * 68 + k] * wt[k * 3 + hh];
        if (ss < 3) feat3p[(size_t)(nbase + ii) * 8 + hh] = acc;   // el3 f32 at 0..2
        else        er3[(size_t)(nbase + ii) * 4 + hh] = acc;
    }
}

// ---------------- layer-3 aggregation v3: 4 lanes/node, no LDS ---------------
__global__ void __launch_bounds__(256, 8) k_agg3(const float* __restrict__ feat3p,
                                                 const float* __restrict__ er3,
                                                 const float* __restrict__ b3,
                                                 const int* __restrict__ rowp,
                                                 const int* __restrict__ col,
                                                 float* __restrict__ out) {
    const int t = threadIdx.x;
    const int lane = t & 63;
    const int i16 = lane >> 2;
    const int j = lane & 3;
    const int n = blockIdx.x * 64 + (t >> 6) * 16 + i16;   // 782 blocks
    const bool valid = (n < N_NODES);
    const int jb = valid ? rowp[n] : 0;
    const int je = valid ? rowp[n + 1] : 0;
    const float4 er4 = valid ? *reinterpret_cast<const float4*>(er3 + (size_t)n * 4)
                             : make_float4(0.f, 0.f, 0.f, 0.f);
    const char* __restrict__ fb = (const char*)feat3p;

    float acc[6];
#pragma unroll
    for (int k = 0; k < 6; ++k) acc[k] = 0.f;
    float sw0 = 0.f, sw1 = 0.f, sw2 = 0.f;

    for (int e = jb + j; e < je; e += 8) {
        const int e2 = e + 4;
        const bool v2 = (e2 < je);
        const int offa = col[e] << 5;
        const int offb = (v2 ? col[e2] : col[e]) << 5;
        const float4 fa1 = *reinterpret_cast<const float4*>(fb + offa);
        const float2 fb1 = *reinterpret_cast<const float2*>(fb + offa + 16);
        const float4 fa2 = *reinterpret_cast<const float4*>(fb + offb);
        const float2 fb2 = *reinterpret_cast<const float2*>(fb + offb + 16);
        const float m2 = v2 ? 1.f : 0.f;
        const float w10 = __expf(lrelu(fa1.x + er4.x));
        const float w11 = __expf(lrelu(fa1.y + er4.y));
        const float w12 = __expf(lrelu(fa1.z + er4.z));
        const float w20 = __expf(lrelu(fa2.x + er4.x)) * m2;
        const float w21 = __expf(lrelu(fa2.y + er4.y)) * m2;
        const float w22 = __expf(lrelu(fa2.z + er4.z)) * m2;
        sw0 += w10 + w20; sw1 += w11 + w21; sw2 += w12 + w22;
        const float2 f01a = h2f(fa1.w), f23a = h2f(fb1.x), f45a = h2f(fb1.y);
        const float2 f01b = h2f(fa2.w), f23b = h2f(fb2.x), f45b = h2f(fb2.y);
        acc[0] += w10 * f01a.x + w20 * f01b.x;
        acc[1] += w10 * f01a.y + w20 * f01b.y;
        acc[2] += w11 * f23a.x + w21 * f23b.x;
        acc[3] += w11 * f23a.y + w21 * f23b.y;
        acc[4] += w12 * f45a.x + w22 * f45b.x;
        acc[5] += w12 * f45a.y + w22 * f45b.y;
    }
#pragma unroll
    for (int off = 1; off < 4; off <<= 1) {
        sw0 += __shfl_xor(sw0, off);
        sw1 += __shfl_xor(sw1, off);
        sw2 += __shfl_xor(sw2, off);
#pragma unroll
        for (int k = 0; k < 6; ++k) acc[k] += __shfl_xor(acc[k], off);
    }
    if (j == 0 && valid) {
        const bool has = (je > jb);
        const float i0 = has ? 1.f / sw0 : 0.f;
        const float i1 = has ? 1.f / sw1 : 0.f;
        const float i2 = has ? 1.f / sw2 : 0.f;
        const float o0 = acc[0] * i0 + acc[2] * i1 + acc[4] * i2 + b3[0] + b3[2] + b3[4];
        const float o1 = acc[1] * i0 + acc[3] * i1 + acc[5] * i2 + b3[1] + b3[3] + b3[5];
        *reinterpret_cast<float2*>(out + (size_t)n * 2) = make_float2(o0, o1);
    }
}

extern "C" void kernel_launch(void* const* d_in, const int* in_sizes, int n_in,
                              void* d_out, int out_size, void* d_ws, size_t ws_size,
                              hipStream_t stream) {
    const float* feats = (const float*)d_in[0];
    const int* src = (const int*)d_in[1];
    const int* dst = (const int*)d_in[2];
    const float* W1 = (const float*)d_in[3];
    const float* al1 = (const float*)d_in[4];
    const float* ar1 = (const float*)d_in[5];
    const float* b1 = (const float*)d_in[6];
    const float* W2 = (const float*)d_in[7];
    const float* al2 = (const float*)d_in[8];
    const float* ar2 = (const float*)d_in[9];
    const float* b2 = (const float*)d_in[10];
    const float* W3 = (const float*)d_in[11];
    const float* al3 = (const float*)d_in[12];
    const float* ar3 = (const float*)d_in[13];
    const float* b3 = (const float*)d_in[14];
    float* out = (float*)d_out;

    char* ws = (char*)d_ws;
    size_t off = 0;
    auto alloc = [&](size_t bytes) {
        void* p = ws + off;
        off += (bytes + 255) & ~(size_t)255;
        return p;
    };
    signed char* hbuf8 = (signed char*)alloc((size_t)N_NODES * 64); // int8 L1 hidden
    float* xph = (float*)alloc((size_t)N_NODES * 8 * 4);         // packed el1(f32)+x(f16)
    float* el = (float*)alloc((size_t)N_NODES * 4 * 4);          // el1..3 (f32) + scale in .w
    float* er = (float*)alloc((size_t)N_NODES * 4 * 4);
    int* bfill = (int*)alloc(256 * 4);
    int* rowp = (int*)alloc((size_t)(N_NODES + 1) * 4);
    int* col = (int*)alloc((size_t)N_EDGES * 4);
    unsigned int* stage = (unsigned int*)alloc((size_t)NBKT * BCAP * 4);  // 3.5 MB
    __half* Wt16 = (__half*)alloc((size_t)64 * 192 * 2);         // 24 KB fp16 W2^T
    float* Wa2 = (float*)alloc(256 * 4);
    float* Wr2 = (float*)alloc(256 * 4);
    float* feat3p = (float*)alloc((size_t)N_NODES * 8 * 4);      // packed el3(f32)+feat(f16)
    (void)ws_size;

    const int qb = N_NODES / 16;            // 16 nodes/block kernels: 3125
    const int nb64 = (N_NODES + 63) / 64;   // 64-nodes/block kernels: 782

    // ---- CSR build + front prep (single edge sweep via fixed-cap buckets) ----
    hipMemsetAsync(bfill, 0, 256 * 4, stream);
    k_front<<<NB_BIN + NB_EL + NB_PW + 1, 256, 0, stream>>>(
        src, dst, bfill, stage, feats, W1, al1, ar1, xph, er, W2, Wt16,
        al2, ar2, Wa2, Wr2);
    k_bscatter2<<<NBKT, 512, 0, stream>>>(stage, bfill, rowp, col);

    // ---- layer 1 (agg + GEMM; int8-quantized hidden out) ----
    k_l1<<<qb, 256, 0, stream>>>(xph, er, rowp, col, W1, b1, Wa2, Wr2, hbuf8, el, er);

    // ---- layer 2 agg (int8 gather) + GEMM + layer-3 features ----
    k_l2<<<qb, 256, 0, stream>>>(hbuf8, el, er, rowp, col, Wt16, b2,
                                 W3, al3, ar3, feat3p, er);

    // ---- layer 3 aggregation ----
    k_agg3<<<nb64, 256, 0, stream>>>(feat3p, er, b3, rowp, col, out);
}

// Round 15
// 188.493 us; speedup vs baseline: 1.0136x; 1.0136x over previous
//
#include <hip/hip_runtime.h>
#include <hip/hip_fp16.h>

#define N_NODES 50000
#define N_EDGES 800000
#define NBKT 196            // ceil(50000 / 256) coarse buckets (dst >> 8)
#define BCAP 4480           // fixed bucket capacity: mean 4083, sd 64 -> +6 sigma
#define EPB_BIN 4096        // edges per staging block
#define NB_BIN ((N_EDGES + EPB_BIN - 1) / EPB_BIN)   // 196
#define NB_EL 196           // ceil(50000/256) blocks for el9p role
#define NB_PW 48            // 64*192/256 blocks for prepW role

typedef _Float16 half8 __attribute__((ext_vector_type(8)));
typedef float f32x4 __attribute__((ext_vector_type(4)));

static __device__ __forceinline__ float lrelu(float x) { return fmaxf(x, 0.2f * x); }

static __device__ __forceinline__ float2 h2f(float bits) {
    union { float f; __half2 h; } u;
    u.f = bits;
    return __half22float2(u.h);
}
static __device__ __forceinline__ float f2h2(float a, float b) {
    union { float f; __half2 h; } u;
    u.h = __floats2half2_rn(a, b);
    return u.f;
}

// ---------------- fused front kernel: stage | el9p | prepW | prepA ----------
__global__ void __launch_bounds__(256) k_front(const int* __restrict__ src,
                                               const int* __restrict__ dst,
                                               int* __restrict__ bfill,
                                               unsigned int* __restrict__ stage,
                                               const float* __restrict__ x,
                                               const float* __restrict__ W1,
                                               const float* __restrict__ al1,
                                               const float* __restrict__ ar1,
                                               float* __restrict__ xph,
                                               float* __restrict__ er,
                                               const float* __restrict__ W2,
                                               __half* __restrict__ Wt16,
                                               const float* __restrict__ al2,
                                               const float* __restrict__ ar2,
                                               float* __restrict__ Wa2,
                                               float* __restrict__ Wr2) {
    __shared__ int lcnt[NBKT];
    __shared__ int gb[NBKT];
    __shared__ int lf[NBKT];
    __shared__ float sWa[9 * 3];
    __shared__ float sWr[9 * 3];
    const int t = threadIdx.x;
    const int b = blockIdx.x;

    if (b < NB_BIN) {
        // ---- role: stage edges into fixed-capacity buckets ----
        const int e0 = b * EPB_BIN;
        for (int i = t; i < NBKT; i += 256) lcnt[i] = 0;
        __syncthreads();
        int dcache[16];
#pragma unroll
        for (int i = 0; i < 16; ++i) {
            const int e = e0 + i * 256 + t;
            if (e < N_EDGES) {
                const int d = dst[e];
                dcache[i] = d;
                atomicAdd(&lcnt[d >> 8], 1);
            } else dcache[i] = -1;
        }
        __syncthreads();
        for (int i = t; i < NBKT; i += 256) {
            gb[i] = i * BCAP + atomicAdd(&bfill[i], lcnt[i]);
            lf[i] = 0;
        }
        __syncthreads();
#pragma unroll
        for (int i = 0; i < 16; ++i) {
            const int e = e0 + i * 256 + t;
            if (e < N_EDGES) {
                const int d = dcache[i];
                const int bk = d >> 8;
                const int r = atomicAdd(&lf[bk], 1);
                stage[gb[bk] + r] = (unsigned int)src[e] | ((unsigned int)(d & 255) << 16);
            }
        }
        return;
    }
    if (b < NB_BIN + NB_EL) {
        // ---- role: layer-1 packed features + er ----
        if (t < 27) {
            const int h = t / 9, k = t % 9;
            float sa = 0.f, sr = 0.f;
            for (int f = 0; f < 64; ++f) {
                const float w = W1[k * 192 + h * 64 + f];
                sa += w * al1[h * 64 + f];
                sr += w * ar1[h * 64 + f];
            }
            sWa[k * 3 + h] = sa;
            sWr[k * 3 + h] = sr;
        }
        __syncthreads();
        const int n = (b - NB_BIN) * 256 + t;
        if (n >= N_NODES) return;
        const float* __restrict__ xr = x + (size_t)n * 9;
        float xv[9];
        float a0 = 0.f, a1 = 0.f, a2 = 0.f, r0 = 0.f, r1 = 0.f, r2 = 0.f;
#pragma unroll
        for (int k = 0; k < 9; ++k) {
            xv[k] = xr[k];
            a0 += xv[k] * sWa[k * 3 + 0];
            a1 += xv[k] * sWa[k * 3 + 1];
            a2 += xv[k] * sWa[k * 3 + 2];
            r0 += xv[k] * sWr[k * 3 + 0];
            r1 += xv[k] * sWr[k * 3 + 1];
            r2 += xv[k] * sWr[k * 3 + 2];
        }
        float* __restrict__ xo = xph + (size_t)n * 8;
        *reinterpret_cast<float4*>(xo) = make_float4(a0, a1, a2, f2h2(xv[0], xv[1]));
        *reinterpret_cast<float4*>(xo + 4) =
            make_float4(f2h2(xv[2], xv[3]), f2h2(xv[4], xv[5]),
                        f2h2(xv[6], xv[7]), f2h2(xv[8], 0.f));
        *reinterpret_cast<float4*>(er + (size_t)n * 4) = make_float4(r0, r1, r2, 0.f);
        return;
    }
    if (b < NB_BIN + NB_EL + NB_PW) {
        // ---- role: W2 -> fp16 effective-transpose table ----
        const int idx = (b - (NB_BIN + NB_EL)) * 256 + t;
        if (idx < 64 * 192) {
            const int n = idx / 192, ke = idx % 192;
            Wt16[idx] = __float2half(W2[(ke & 63) * 192 + (ke >> 6) * 64 + n]);
        }
        return;
    }
    // ---- role: Wa2/Wr2 precompute ----
    if (t < 192) {
        const int h = t >> 6, k = t & 63;
        float sa = 0.f, sr = 0.f;
        for (int f = 0; f < 64; ++f) {
            const float w = W2[k * 192 + h * 64 + f];
            sa += w * al2[h * 64 + f];
            sr += w * ar2[h * 64 + f];
        }
        Wa2[k * 4 + h] = sa;
        Wr2[k * 4 + h] = sr;
        if (h == 0) { Wa2[k * 4 + 3] = 0.f; Wr2[k * 4 + 3] = 0.f; }
    }
}

// ---------------- per bucket scatter v2: shfl scans --------------------------
__global__ void __launch_bounds__(512) k_bscatter2(const unsigned int* __restrict__ stage,
                                                   const int* __restrict__ bfill,
                                                   int* __restrict__ rowp,
                                                   int* __restrict__ col) {
    __shared__ int lcnt[256];
    __shared__ int sexc[256];
    __shared__ int wsum[8];
    __shared__ int sbase;
    const int t = threadIdx.x;
    const int lane = t & 63;
    const int w = t >> 6;
    const int b = blockIdx.x;
    const int n0 = b << 8;

    int p = (t < b) ? bfill[t] : 0;
#pragma unroll
    for (int off = 32; off > 0; off >>= 1) p += __shfl_xor(p, off);
    if (lane == 0) wsum[w] = p;
    if (t < 256) lcnt[t] = 0;
    __syncthreads();
    if (t == 0) {
        int s = 0;
#pragma unroll
        for (int i = 0; i < 8; ++i) s += wsum[i];
        sbase = s;
    }
    const int cnt = bfill[b];
    const unsigned int* __restrict__ st = stage + (size_t)b * BCAP;
    for (int j = t; j < cnt; j += 512)
        atomicAdd(&lcnt[(st[j] >> 16) & 255], 1);
    __syncthreads();
    int v = 0, s = 0;
    if (t < 256) {
        v = lcnt[t];
        s = v;
#pragma unroll
        for (int off = 1; off < 64; off <<= 1) {
            const int u = __shfl_up(s, off);
            if (lane >= off) s += u;
        }
        if (lane == 63) wsum[w] = s;
    }
    __syncthreads();
    const int base = sbase;
    if (t < 256) {
        int add = 0;
        for (int i = 0; i < w; ++i) add += wsum[i];
        const int exc = s + add - v;
        sexc[t] = exc;
        if (n0 + t < N_NODES) rowp[n0 + t] = base + exc;
        lcnt[t] = 0;   // reuse as fill counters
    }
    if (b == NBKT - 1 && t == 0) rowp[N_NODES] = N_EDGES;
    __syncthreads();
    for (int j = t; j < cnt; j += 512) {
        const unsigned int e = st[j];
        const int local = (int)(e >> 16) & 255;
        const int r = atomicAdd(&lcnt[local], 1);
        col[base + sexc[local] + r] = (int)(e & 0xFFFFu);
    }
}

// ---------------- fused L1 v5: v4 agg + int8-quantized hidden output ---------
// hout int8 per-node-scaled (scale = rowmax/127, stored in el[n].w).
// Scale folds into edge weights in k_l2 (softmax denominator unscaled).
__global__ void __launch_bounds__(256, 6) k_l1(const float* __restrict__ xph,
                                               const float* __restrict__ er_in,
                                               const int* __restrict__ rowp,
                                               const int* __restrict__ col,
                                               const float* __restrict__ W1,
                                               const float* __restrict__ b1,
                                               const float* __restrict__ Wa2,
                                               const float* __restrict__ Wr2,
                                               signed char* __restrict__ hout8,
                                               float* __restrict__ el,
                                               float* __restrict__ er_out) {
    __shared__ float4 wbuf[4][4][16];   // (w0,w1,w2,rowoff) per edge, per node
    __shared__ union {
        float At[16 * 28];          // agg -> gemm handoff (dead after part compute)
        float vbuf[16][72];         // gemm epilogue staging (aliases At; sync between)
    } u;
    __shared__ float part[3][16][64];
    __shared__ float sscale[16];
    const int t = threadIdx.x;
    const int wv = t >> 6;
    const int lane = t & 63;
    const int q = lane >> 4;            // node slot within wave
    const int ql = lane & 15;           // lane within quarter
    const int li = wv * 4 + q;          // local node 0..15
    const int nbase = blockIdx.x * 16;  // 3125 * 16 = 50000 exact
    const int n = nbase + li;
    const char* __restrict__ xb = (const char*)xph;

    // ---- aggregation: el-phase lane/edge, x-phase 5-lane half2 ----
    {
        const int jb = rowp[n], je = rowp[n + 1];
        const float4 er4 = *reinterpret_cast<const float4*>(er_in + (size_t)n * 4);
        const int fo = 12 + 4 * ql;     // lane's half2 byte offset (valid for ql<5)
        float a00 = 0.f, a01 = 0.f, a10 = 0.f, a11 = 0.f, a20 = 0.f, a21 = 0.f;
        float sw0 = 0.f, sw1 = 0.f, sw2 = 0.f;

        for (int c0 = jb; c0 < je; c0 += 16) {
            const int cnt = min(16, je - c0);
            if (ql < cnt) {
                const int s = col[c0 + ql];
                const float4 e4 = *reinterpret_cast<const float4*>(xb + (s << 5));
                const float w0 = __expf(lrelu(e4.x + er4.x));
                const float w1 = __expf(lrelu(e4.y + er4.y));
                const float w2 = __expf(lrelu(e4.z + er4.z));
                wbuf[wv][q][ql] = make_float4(w0, w1, w2, __int_as_float(s << 5));
                sw0 += w0; sw1 += w1; sw2 += w2;
            }
            __builtin_amdgcn_wave_barrier();
            if (ql < 5) {
                int k = 0;
                for (; k + 2 <= cnt; k += 2) {
                    const float4 q0 = wbuf[wv][q][k];
                    const float4 q1 = wbuf[wv][q][k + 1];
                    const float2 f0 = h2f(*reinterpret_cast<const float*>(
                        xb + (__float_as_int(q0.w) + fo)));
                    const float2 f1 = h2f(*reinterpret_cast<const float*>(
                        xb + (__float_as_int(q1.w) + fo)));
                    a00 += q0.x * f0.x + q1.x * f1.x;
                    a01 += q0.x * f0.y + q1.x * f1.y;
                    a10 += q0.y * f0.x + q1.y * f1.x;
                    a11 += q0.y * f0.y + q1.y * f1.y;
                    a20 += q0.z * f0.x + q1.z * f1.x;
                    a21 += q0.z * f0.y + q1.z * f1.y;
                }
                if (k < cnt) {
                    const float4 q0 = wbuf[wv][q][k];
                    const float2 f0 = h2f(*reinterpret_cast<const float*>(
                        xb + (__float_as_int(q0.w) + fo)));
                    a00 += q0.x * f0.x; a01 += q0.x * f0.y;
                    a10 += q0.y * f0.x; a11 += q0.y * f0.y;
                    a20 += q0.z * f0.x; a21 += q0.z * f0.y;
                }
            }
        }
#pragma unroll
        for (int off = 1; off < 16; off <<= 1) {
            sw0 += __shfl_xor(sw0, off);
            sw1 += __shfl_xor(sw1, off);
            sw2 += __shfl_xor(sw2, off);
        }
        if (ql < 5) {
            const bool has = (je > jb);
            const float i0 = has ? 1.f / sw0 : 0.f;
            const float i1 = has ? 1.f / sw1 : 0.f;
            const float i2 = has ? 1.f / sw2 : 0.f;
            float* __restrict__ ao = u.At + li * 28;
            const int f = 2 * ql;
            ao[f] = a00 * i0;
            ao[9 + f] = a10 * i1;
            ao[18 + f] = a20 * i2;
            if (ql < 4) {                // f8's pair slot is head-1's slot 9 — guard
                ao[f + 1] = a01 * i0;
                ao[9 + f + 1] = a11 * i1;
                ao[18 + f + 1] = a21 * i2;
            }
        }
    }
    __syncthreads();

    // ---- GEMM (h = wave id, c = lane) + int8 quantized store ----
    {
        const int h = wv;               // 0..3; h==3 idle for partials
        const int c = lane;
        if (h < 3) {
            float wreg[9];
#pragma unroll
            for (int k = 0; k < 9; ++k) wreg[k] = W1[k * 192 + h * 64 + c];
#pragma unroll
            for (int i = 0; i < 16; ++i) {
                const float* __restrict__ arp = u.At + i * 28 + h * 9;
                float acc = 0.f;
#pragma unroll
                for (int k = 0; k < 9; ++k) acc += arp[k] * wreg[k];
                part[h][i][c] = acc;
            }
        }
        __syncthreads();
        const float bsum = b1[c] + b1[64 + c] + b1[128 + c];
        for (int idx = t; idx < 1024; idx += 256) {
            const int i = idx >> 6, cc = idx & 63;  // cc == lane; wave owns node i
            const float v = part[0][i][cc] + part[1][i][cc] + part[2][i][cc] + bsum;
            u.vbuf[i][cc] = v;           // aliases At — legal: At dead, sync above
            float av = fabsf(v);
#pragma unroll
            for (int off = 32; off > 0; off >>= 1) av = fmaxf(av, __shfl_xor(av, off));
            const float inv = (av > 0.f) ? 127.f / av : 0.f;
            hout8[(size_t)(nbase + i) * 64 + cc] = (signed char)__float2int_rn(v * inv);
            if (cc == 0) sscale[i] = av * (1.f / 127.f);
        }
        __syncthreads();
        if (t < 96) {
            const int i = t / 6, r = t % 6;
            const int h3 = (r < 3) ? r : r - 3;
            const float* __restrict__ tab = (r < 3) ? Wa2 : Wr2;
            float s = 0.f;
#pragma unroll 8
            for (int c2 = 0; c2 < 64; ++c2) s += u.vbuf[i][c2] * tab[c2 * 4 + h3];
            if (r < 3) el[(size_t)(nbase + i) * 4 + h3] = s;
            else       er_out[(size_t)(nbase + i) * 4 + h3] = s;
        } else if (t < 112) {
            const int i = t - 96;        // scale rides in el.w (was unused pad)
            el[(size_t)(nbase + i) * 4 + 3] = sscale[i];
        }
    }
}

// ---------------- fused L2: int8-gather agg + MFMA GEMM + L3 features --------
// x rows are int8 (64B); dequant scale comes free in el[s].w and folds into
// the edge weights (after sw accumulation -> softmax exact).
__global__ void __launch_bounds__(256, 6) k_l2(const signed char* __restrict__ x8,
                                               const float* __restrict__ el,
                                               const float* __restrict__ er,
                                               const int* __restrict__ rowp,
                                               const int* __restrict__ col,
                                               const __half* __restrict__ Wt,
                                               const float* __restrict__ b2,
                                               const float* __restrict__ W3,
                                               const float* __restrict__ al3,
                                               const float* __restrict__ ar3,
                                               float* __restrict__ feat3p,
                                               float* __restrict__ er3) {
    __shared__ float4 wbuf[4][4][16];     // 4 KB
    __shared__ __half aggL[16][200];      // 6.25 KB (pad 192->200)
    __shared__ float xl[16 * 68];         // 4.25 KB
    __shared__ float Wl[384];
    __shared__ float Wal[192];
    __shared__ float Wrl[192];
    const int t = threadIdx.x;
    const int wv = t >> 6;
    const int lane = t & 63;
    const int q = lane >> 4;              // node slot within wave
    const int ql = lane & 15;             // lane within quarter
    const int li = wv * 4 + q;            // local node 0..15
    const int nbase = blockIdx.x * 16;    // 3125 * 16 = 50000 exact
    const int n = nbase + li;

    // ---- Phase A: aggregation (int8 gather, 4B/lane) ----
    {
        const int jb = rowp[n], je = rowp[n + 1];
        const float4 er4 = *reinterpret_cast<const float4*>(er + (size_t)n * 4);
        const char* __restrict__ xbase = (const char*)x8;
        const char* __restrict__ elbase = (const char*)el;
        const int foff = ql * 4;          // 4 int8 feats per lane

        float acc[12];
#pragma unroll
        for (int j = 0; j < 12; ++j) acc[j] = 0.f;
        float sw0 = 0.f, sw1 = 0.f, sw2 = 0.f;

        for (int c0 = jb; c0 < je; c0 += 16) {
            const int cnt = min(16, je - c0);
            if (ql < cnt) {
                const int s = col[c0 + ql];
                const float4 e4 = *reinterpret_cast<const float4*>(elbase + (s << 4));
                const float w0 = __expf(lrelu(e4.x + er4.x));
                const float w1 = __expf(lrelu(e4.y + er4.y));
                const float w2 = __expf(lrelu(e4.z + er4.z));
                sw0 += w0; sw1 += w1; sw2 += w2;
                // fold dequant scale (el.w) into the weights; sw stays unscaled
                wbuf[wv][q][ql] = make_float4(w0 * e4.w, w1 * e4.w, w2 * e4.w,
                                              __int_as_float(s << 6));
            }
            __builtin_amdgcn_wave_barrier();
            int k = 0;
            for (; k + 4 <= cnt; k += 4) {
                const float4 q0 = wbuf[wv][q][k];
                const float4 q1 = wbuf[wv][q][k + 1];
                const float4 q2 = wbuf[wv][q][k + 2];
                const float4 q3 = wbuf[wv][q][k + 3];
                const int d0 = *reinterpret_cast<const int*>(xbase + (__float_as_int(q0.w) + foff));
                const int d1 = *reinterpret_cast<const int*>(xbase + (__float_as_int(q1.w) + foff));
                const int d2 = *reinterpret_cast<const int*>(xbase + (__float_as_int(q2.w) + foff));
                const int d3 = *reinterpret_cast<const int*>(xbase + (__float_as_int(q3.w) + foff));
                const float a0 = (float)(signed char)d0, a1 = (float)(signed char)(d0 >> 8),
                            a2 = (float)(signed char)(d0 >> 16), a3 = (float)(d0 >> 24);
                const float b0 = (float)(signed char)d1, b1v = (float)(signed char)(d1 >> 8),
                            b2v = (float)(signed char)(d1 >> 16), b3v = (float)(d1 >> 24);
                const float c0v = (float)(signed char)d2, c1 = (float)(signed char)(d2 >> 8),
                            c2 = (float)(signed char)(d2 >> 16), c3 = (float)(d2 >> 24);
                const float e0 = (float)(signed char)d3, e1 = (float)(signed char)(d3 >> 8),
                            e2 = (float)(signed char)(d3 >> 16), e3 = (float)(d3 >> 24);
                acc[0] += q0.x * a0 + q1.x * b0 + q2.x * c0v + q3.x * e0;
                acc[1] += q0.x * a1 + q1.x * b1v + q2.x * c1 + q3.x * e1;
                acc[2] += q0.x * a2 + q1.x * b2v + q2.x * c2 + q3.x * e2;
                acc[3] += q0.x * a3 + q1.x * b3v + q2.x * c3 + q3.x * e3;
                acc[4] += q0.y * a0 + q1.y * b0 + q2.y * c0v + q3.y * e0;
                acc[5] += q0.y * a1 + q1.y * b1v + q2.y * c1 + q3.y * e1;
                acc[6] += q0.y * a2 + q1.y * b2v + q2.y * c2 + q3.y * e2;
                acc[7] += q0.y * a3 + q1.y * b3v + q2.y * c3 + q3.y * e3;
                acc[8]  += q0.z * a0 + q1.z * b0 + q2.z * c0v + q3.z * e0;
                acc[9]  += q0.z * a1 + q1.z * b1v + q2.z * c1 + q3.z * e1;
                acc[10] += q0.z * a2 + q1.z * b2v + q2.z * c2 + q3.z * e2;
                acc[11] += q0.z * a3 + q1.z * b3v + q2.z * c3 + q3.z * e3;
            }
            for (; k < cnt; ++k) {
                const float4 q0 = wbuf[wv][q][k];
                const int d0 = *reinterpret_cast<const int*>(xbase + (__float_as_int(q0.w) + foff));
                const float a0 = (float)(signed char)d0, a1 = (float)(signed char)(d0 >> 8),
                            a2 = (float)(signed char)(d0 >> 16), a3 = (float)(d0 >> 24);
                acc[0] += q0.x * a0; acc[1] += q0.x * a1;
                acc[2] += q0.x * a2; acc[3] += q0.x * a3;
                acc[4] += q0.y * a0; acc[5] += q0.y * a1;
                acc[6] += q0.y * a2; acc[7] += q0.y * a3;
                acc[8]  += q0.z * a0; acc[9]  += q0.z * a1;
                acc[10] += q0.z * a2; acc[11] += q0.z * a3;
            }
        }
#pragma unroll
        for (int off = 1; off < 16; off <<= 1) {
            sw0 += __shfl_xor(sw0, off);
            sw1 += __shfl_xor(sw1, off);
            sw2 += __shfl_xor(sw2, off);
        }
        __half* __restrict__ ao = &aggL[li][ql * 4];
        if (je > jb) {
            const float i0 = 1.f / sw0, i1 = 1.f / sw1, i2 = 1.f / sw2;
            *reinterpret_cast<float2*>(ao) =
                make_float2(f2h2(acc[0] * i0, acc[1] * i0), f2h2(acc[2] * i0, acc[3] * i0));
            *reinterpret_cast<float2*>(ao + 64) =
                make_float2(f2h2(acc[4] * i1, acc[5] * i1), f2h2(acc[6] * i1, acc[7] * i1));
            *reinterpret_cast<float2*>(ao + 128) =
                make_float2(f2h2(acc[8] * i2, acc[9] * i2), f2h2(acc[10] * i2, acc[11] * i2));
        } else {
            const float2 z = make_float2(f2h2(0.f, 0.f), f2h2(0.f, 0.f));
            *reinterpret_cast<float2*>(ao) = z;
            *reinterpret_cast<float2*>(ao + 64) = z;
            *reinterpret_cast<float2*>(ao + 128) = z;
        }
    }
    // weight prep for phase C (disjoint LDS; before the sync)
    for (int idx = t; idx < 384; idx += 256) Wl[idx] = W3[idx];
    if (t < 192) {
        const int k = t & 63, h = t >> 6;
        Wal[k * 3 + h] = W3[k * 6 + h * 2] * al3[h * 2] + W3[k * 6 + h * 2 + 1] * al3[h * 2 + 1];
        Wrl[k * 3 + h] = W3[k * 6 + h * 2] * ar3[h * 2] + W3[k * 6 + h * 2 + 1] * ar3[h * 2 + 1];
    }
    __syncthreads();

    // ---- Phase B: MFMA hidden = aggL @ W2^T + b2sum -> xl (LDS) ----
    {
        const int quad = lane >> 4;
        const int t16 = lane & 15;
        half8 a[6];
#pragma unroll
        for (int kb = 0; kb < 6; ++kb)
            a[kb] = *reinterpret_cast<const half8*>(&aggL[t16][kb * 32 + quad * 8]);
        const int c = wv * 16 + t16;          // nt = wv
        const float bs = b2[c] + b2[64 + c] + b2[128 + c];
        const __half* __restrict__ bt = Wt + (size_t)c * 192 + quad * 8;
        f32x4 acc = {0.f, 0.f, 0.f, 0.f};
#pragma unroll
        for (int kb = 0; kb < 6; ++kb) {
            const half8 bfr = *reinterpret_cast<const half8*>(bt + kb * 32);
            acc = __builtin_amdgcn_mfma_f32_16x16x32_f16(a[kb], bfr, acc, 0, 0, 0);
        }
#pragma unroll
        for (int r = 0; r < 4; ++r)
            xl[(quad * 4 + r) * 68 + c] = acc[r] + bs;
    }
    __syncthreads();

    // ---- Phase C: layer-3 packed features for the block's 16 nodes ----
    if (t < 128) {
        const int i = t >> 3;
        const int slot = t & 7;
        if (slot < 6) {
            float acc = 0.f;
#pragma unroll
            for (int k4 = 0; k4 < 16; ++k4) {
                const float4 xv = *reinterpret_cast<const float4*>(&xl[i * 68 + 4 * k4]);
                acc += Wl[(4 * k4 + 0) * 6 + slot] * xv.x;
                acc += Wl[(4 * k4 + 1) * 6 + slot] * xv.y;
                acc += Wl[(4 * k4 + 2) * 6 + slot] * xv.z;
                acc += Wl[(4 * k4 + 3) * 6 + slot] * xv.w;
            }
            reinterpret_cast<__half*>(feat3p + (size_t)(nbase + i) * 8)[6 + slot] = __float2half(acc);
        }
    } else if (t < 224) {
        const int tt = t - 128;
        const int ii = tt / 6, ss = tt % 6;
        const int hh = (ss < 3) ? ss : ss - 3;
        const float* __restrict__ wt = (ss < 3) ? Wal : Wrl;
        float acc = 0.f;
#pragma unroll 4
        for (int k = 0; k < 64; ++k) acc += xl[ii * 68 + k] * wt[k * 3 + hh];
        if (ss < 3) feat3p[(size_t)(nbase + ii) * 8 + hh] = acc;   // el3 f32 at 0..2
        else        er3[(size_t)(nbase + ii) * 4 + hh] = acc;
    }
}

// ---------------- layer-3 aggregation v3: 4 lanes/node, no LDS ---------------
__global__ void __launch_bounds__(256, 8) k_agg3(const float* __restrict__ feat3p,
                                                 const float* __restrict__ er3,
                                                 const float* __restrict__ b3,
                                                 const int* __restrict__ rowp,
                                                 const int* __restrict__ col,
                                                 float* __restrict__ out) {
    const int t = threadIdx.x;
    const int lane = t & 63;
    const int i16 = lane >> 2;
    const int j = lane & 3;
    const int n = blockIdx.x * 64 + (t >> 6) * 16 + i16;   // 782 blocks
    const bool valid = (n < N_NODES);
    const int jb = valid ? rowp[n] : 0;
    const int je = valid ? rowp[n + 1] : 0;
    const float4 er4 = valid ? *reinterpret_cast<const float4*>(er3 + (size_t)n * 4)
                             : make_float4(0.f, 0.f, 0.f, 0.f);
    const char* __restrict__ fb = (const char*)feat3p;

    float acc[6];
#pragma unroll
    for (int k = 0; k < 6; ++k) acc[k] = 0.f;
    float sw0 = 0.f, sw1 = 0.f, sw2 = 0.f;

    for (int e = jb + j; e < je; e += 8) {
        const int e2 = e + 4;
        const bool v2 = (e2 < je);
        const int offa = col[e] << 5;
        const int offb = (v2 ? col[e2] : col[e]) << 5;
        const float4 fa1 = *reinterpret_cast<const float4*>(fb + offa);
        const float2 fb1 = *reinterpret_cast<const float2*>(fb + offa + 16);
        const float4 fa2 = *reinterpret_cast<const float4*>(fb + offb);
        const float2 fb2 = *reinterpret_cast<const float2*>(fb + offb + 16);
        const float m2 = v2 ? 1.f : 0.f;
        const float w10 = __expf(lrelu(fa1.x + er4.x));
        const float w11 = __expf(lrelu(fa1.y + er4.y));
        const float w12 = __expf(lrelu(fa1.z + er4.z));
        const float w20 = __expf(lrelu(fa2.x + er4.x)) * m2;
        const float w21 = __expf(lrelu(fa2.y + er4.y)) * m2;
        const float w22 = __expf(lrelu(fa2.z + er4.z)) * m2;
        sw0 += w10 + w20; sw1 += w11 + w21; sw2 += w12 + w22;
        const float2 f01a = h2f(fa1.w), f23a = h2f(fb1.x), f45a = h2f(fb1.y);
        const float2 f01b = h2f(fa2.w), f23b = h2f(fb2.x), f45b = h2f(fb2.y);
        acc[0] += w10 * f01a.x + w20 * f01b.x;
        acc[1] += w10 * f01a.y + w20 * f01b.y;
        acc[2] += w11 * f23a.x + w21 * f23b.x;
        acc[3] += w11 * f23a.y + w21 * f23b.y;
        acc[4] += w12 * f45a.x + w22 * f45b.x;
        acc[5] += w12 * f45a.y + w22 * f45b.y;
    }
#pragma unroll
    for (int off = 1; off < 4; off <<= 1) {
        sw0 += __shfl_xor(sw0, off);
        sw1 += __shfl_xor(sw1, off);
        sw2 += __shfl_xor(sw2, off);
#pragma unroll
        for (int k = 0; k < 6; ++k) acc[k] += __shfl_xor(acc[k], off);
    }
    if (j == 0 && valid) {
        const bool has = (je > jb);
        const float i0 = has ? 1.f / sw0 : 0.f;
        const float i1 = has ? 1.f / sw1 : 0.f;
        const float i2 = has ? 1.f / sw2 : 0.f;
        const float o0 = acc[0] * i0 + acc[2] * i1 + acc[4] * i2 + b3[0] + b3[2] + b3[4];
        const float o1 = acc[1] * i0 + acc[3] * i1 + acc[5] * i2 + b3[1] + b3[3] + b3[5];
        *reinterpret_cast<float2*>(out + (size_t)n * 2) = make_float2(o0, o1);
    }
}

extern "C" void kernel_launch(void* const* d_in, const int* in_sizes, int n_in,
                              void* d_out, int out_size, void* d_ws, size_t ws_size,
                              hipStream_t stream) {
    const float* feats = (const float*)d_in[0];
    const int* src = (const int*)d_in[1];
    const int* dst = (const int*)d_in[2];
    const float* W1 = (const float*)d_in[3];
    const float* al1 = (const float*)d_in[4];
    const float* ar1 = (const float*)d_in[5];
    const float* b1 = (const float*)d_in[6];
    const float* W2 = (const float*)d_in[7];
    const float* al2 = (const float*)d_in[8];
    const float* ar2 = (const float*)d_in[9];
    const float* b2 = (const float*)d_in[10];
    const float* W3 = (const float*)d_in[11];
    const float* al3 = (const float*)d_in[12];
    const float* ar3 = (const float*)d_in[13];
    const float* b3 = (const float*)d_in[14];
    float* out = (float*)d_out;

    char* ws = (char*)d_ws;
    size_t off = 0;
    auto alloc = [&](size_t bytes) {
        void* p = ws + off;
        off += (bytes + 255) & ~(size_t)255;
        return p;
    };
    signed char* hbuf8 = (signed char*)alloc((size_t)N_NODES * 64); // int8 L1 hidden
    float* xph = (float*)alloc((size_t)N_NODES * 8 * 4);         // packed el1(f32)+x(f16)
    float* el = (float*)alloc((size_t)N_NODES * 4 * 4);          // el1..3 (f32) + scale in .w
    float* er = (float*)alloc((size_t)N_NODES * 4 * 4);
    int* bfill = (int*)alloc(256 * 4);
    int* rowp = (int*)alloc((size_t)(N_NODES + 1) * 4);
    int* col = (int*)alloc((size_t)N_EDGES * 4);
    unsigned int* stage = (unsigned int*)alloc((size_t)NBKT * BCAP * 4);  // 3.5 MB
    __half* Wt16 = (__half*)alloc((size_t)64 * 192 * 2);         // 24 KB fp16 W2^T
    float* Wa2 = (float*)alloc(256 * 4);
    float* Wr2 = (float*)alloc(256 * 4);
    float* feat3p = (float*)alloc((size_t)N_NODES * 8 * 4);      // packed el3(f32)+feat(f16)
    (void)ws_size;

    const int qb = N_NODES / 16;            // 16 nodes/block kernels: 3125
    const int nb64 = (N_NODES + 63) / 64;   // 64-nodes/block kernels: 782

    // ---- CSR build + front prep (single edge sweep via fixed-cap buckets) ----
    hipMemsetAsync(bfill, 0, 256 * 4, stream);
    k_front<<<NB_BIN + NB_EL + NB_PW + 1, 256, 0, stream>>>(
        src, dst, bfill, stage, feats, W1, al1, ar1, xph, er, W2, Wt16,
        al2, ar2, Wa2, Wr2);
    k_bscatter2<<<NBKT, 512, 0, stream>>>(stage, bfill, rowp, col);

    // ---- layer 1 (agg + GEMM; int8-quantized hidden out) ----
    k_l1<<<qb, 256, 0, stream>>>(xph, er, rowp, col, W1, b1, Wa2, Wr2, hbuf8, el, er);

    // ---- layer 2 agg (int8 gather) + GEMM + layer-3 features ----
    k_l2<<<qb, 256, 0, stream>>>(hbuf8, el, er, rowp, col, Wt16, b2,
                                 W3, al3, ar3, feat3p, er);

    // ---- layer 3 aggregation ----
    k_agg3<<<nb64, 256, 0, stream>>>(feat3p, er, b3, rowp, col, out);
}